// Round 4
// baseline (1573.071 us; speedup 1.0000x reference)
//
#include <hip/hip_runtime.h>
#include <hip/hip_bf16.h>

#define H 64
#define NXCD 8
#define CAP 64   // Poisson(20) tail @64 ~ 5e-14/node -> no realistic overflow

// ---------------------------------------------------------------- bucket fill
// XCD-partitioned: group g = blockIdx&7 owns node chunk g for BOTH directions.
// One atomic per edge per direction; counts come free in cur_*.
__global__ void bucket_fill(const int* __restrict__ eidx,
                            int* __restrict__ cur_t, int* __restrict__ cur_s,
                            unsigned* __restrict__ bkt_t, unsigned* __restrict__ bkt_s,
                            int E, int NNt, int NNs) {
    int g = blockIdx.x & (NXCD - 1);
    int bg = blockIdx.x >> 3;
    int nbg = gridDim.x >> 3;
    int CSt = (NNt + NXCD - 1) >> 3;
    int CSs = (NNs + NXCD - 1) >> 3;
    int lot = g * CSt, hit = lot + CSt;
    int los = g * CSs, his = los + CSs;
    int stride = nbg * blockDim.x;
    for (int e = bg * blockDim.x + threadIdx.x; e < E; e += stride) {
        int s = eidx[e];
        int d = eidx[E + e];
        if (d >= lot && d < hit) {
            int p = atomicAdd(&cur_t[d], 1);
            if (p < CAP) bkt_t[((size_t)d << 6) + p] = (unsigned)s;
        }
        if (s >= los && s < his) {
            int p = atomicAdd(&cur_s[s], 1);
            if (p < CAP) bkt_s[((size_t)s << 6) + p] = (unsigned)d;
        }
    }
}

// ---------------------------------------------------------------- fused SAGE layer
// out[node][:] = act( mean_{i in bkt[node]} xs[i][:] @ Wl + xd[node][:] @ Wr + b )
// One wave per node per it; lane j owns output col j and holds Wl/Wr col j in regs.
// Agg phase: 16 lanes x float4 per row (R2-proven pattern), reduce over q, park in LDS.
template <bool RELU>
__global__ __launch_bounds__(256, 2) void sage_layer(
        const float* __restrict__ xs, const float* __restrict__ xd,
        const unsigned* __restrict__ bkt, const int* __restrict__ cur,
        const float* __restrict__ Wl, const float* __restrict__ Wr,
        const float* __restrict__ b, float* __restrict__ out, int n) {
    int tid = threadIdx.x;
    int wv = tid >> 6, lane = tid & 63;
    int q = lane >> 4, p = lane & 15;
    float wl[H], wr[H];
#pragma unroll
    for (int k = 0; k < H; k++) {
        wl[k] = Wl[k * H + lane];
        wr[k] = Wr[k * H + lane];
    }
    float bj = b[lane];
    __shared__ float4 aggl[4][16];
    int base = blockIdx.x * 64;
    for (int it = 0; it < 16; ++it) {
        int node = base + it * 4 + wv;
        bool valid = node < n;
        if (valid) {
            int c = min(cur[node], CAP);
            const unsigned* brow = bkt + ((size_t)node << 6);
            float4 acc = {0.f, 0.f, 0.f, 0.f};
            for (int k = q; k < c; k += 4) {
                int idx = (int)brow[k];
                float4 v = ((const float4*)(xs + (size_t)idx * H))[p];
                acc.x += v.x; acc.y += v.y; acc.z += v.z; acc.w += v.w;
            }
#pragma unroll
            for (int m = 16; m <= 32; m <<= 1) {
                acc.x += __shfl_xor(acc.x, m, 64);
                acc.y += __shfl_xor(acc.y, m, 64);
                acc.z += __shfl_xor(acc.z, m, 64);
                acc.w += __shfl_xor(acc.w, m, 64);
            }
            if (q == 0) {
                float inv = 1.f / fmaxf((float)c, 1.f);
                float4 r = {acc.x * inv, acc.y * inv, acc.z * inv, acc.w * inv};
                aggl[wv][p] = r;
            }
        }
        __syncthreads();
        if (valid) {
            const float4* xv = (const float4*)(xd + (size_t)node * H);
            float acc = bj;
#pragma unroll
            for (int k4 = 0; k4 < 16; k4++) {
                float4 a = aggl[wv][k4];
                float4 xx = xv[k4];
                acc += a.x * wl[4 * k4 + 0] + a.y * wl[4 * k4 + 1] +
                       a.z * wl[4 * k4 + 2] + a.w * wl[4 * k4 + 3];
                acc += xx.x * wr[4 * k4 + 0] + xx.y * wr[4 * k4 + 1] +
                       xx.z * wr[4 * k4 + 2] + xx.w * wr[4 * k4 + 3];
            }
            out[(size_t)node * H + lane] = RELU ? fmaxf(acc, 0.f) : acc;
        }
        __syncthreads();  // protect aggl before next it overwrites
    }
}

// ---------------------------------------------------------------- link scores
// 16 lanes per label edge, float4 loads, 4 edges per wave
__global__ void dot_kernel(const float* __restrict__ os, const float* __restrict__ ot,
                           const int* __restrict__ ell, float* __restrict__ out, int ne) {
    int wv = threadIdx.x >> 6, lane = threadIdx.x & 63;
    int q = lane >> 4, p = lane & 15;
    int l = (blockIdx.x * 4 + wv) * 4 + q;
    if (l >= ne) return;
    int s = ell[l];
    int d = ell[ne + l];
    float4 a = *(const float4*)(os + (size_t)s * H + p * 4);
    float4 b = *(const float4*)(ot + (size_t)d * H + p * 4);
    float pr = a.x * b.x + a.y * b.y + a.z * b.z + a.w * b.w;
#pragma unroll
    for (int m = 1; m <= 8; m <<= 1) pr += __shfl_xor(pr, m, 64);
    if (p == 0) out[l] = pr;
}

// ----------------------------------------------------------------
static inline size_t alignup(size_t x) { return (x + 255) & ~(size_t)255; }

extern "C" void kernel_launch(void* const* d_in, const int* in_sizes, int n_in,
                              void* d_out, int out_size, void* d_ws, size_t ws_size,
                              hipStream_t stream) {
    const float* src_emb = (const float*)d_in[0];
    const float* tgt_emb = (const float*)d_in[1];
    const float* Wl_st1 = (const float*)d_in[2];
    const float* Wr_st1 = (const float*)d_in[3];
    const float* b_st1 = (const float*)d_in[4];
    const float* Wl_ts1 = (const float*)d_in[5];
    const float* Wr_ts1 = (const float*)d_in[6];
    const float* b_ts1 = (const float*)d_in[7];
    const float* Wl_st2 = (const float*)d_in[8];
    const float* Wr_st2 = (const float*)d_in[9];
    const float* b_st2 = (const float*)d_in[10];
    const float* Wl_ts2 = (const float*)d_in[11];
    const float* Wr_ts2 = (const float*)d_in[12];
    const float* b_ts2 = (const float*)d_in[13];
    const int* eidx = (const int*)d_in[14];
    const int* ell = (const int*)d_in[15];

    const int NS = in_sizes[0] / H;
    const int NT = in_sizes[1] / H;
    const int E = in_sizes[14] / 2;
    const int EL = in_sizes[15] / 2;
    const int NN = NT;  // NS == NT here

    // ws budget-conscious layout (~128.8 MB total; R3's 154 MB likely overflowed ws)
    char* ws = (char*)d_ws;
    size_t o_cur = 0;                                       // cur_t, cur_s : 2*NN ints
    size_t o_bkt_t = alignup(o_cur + (size_t)2 * NN * 4);   // NN*CAP uints
    size_t o_bkt_s = alignup(o_bkt_t + (size_t)NN * CAP * 4);
    size_t o_ht = alignup(o_bkt_s + (size_t)NN * CAP * 4);
    size_t o_hs = alignup(o_ht + (size_t)NN * H * 4);
    size_t o_ot = alignup(o_hs + (size_t)NN * H * 4);

    int* cur_t = (int*)(ws + o_cur);
    int* cur_s = cur_t + NN;
    unsigned* bkt_t = (unsigned*)(ws + o_bkt_t);
    unsigned* bkt_s = (unsigned*)(ws + o_bkt_s);
    float* h_t = (float*)(ws + o_ht);
    float* h_s = (float*)(ws + o_hs);
    float* o_t = (float*)(ws + o_ot);
    float* out = (float*)d_out;

    hipMemsetAsync(ws + o_cur, 0, (size_t)2 * NN * 4, stream);

    bucket_fill<<<2048, 256, 0, stream>>>(eidx, cur_t, cur_s, bkt_t, bkt_s, E, NT, NS);

    int glt = (NT + 63) / 64;
    int gls = (NS + 63) / 64;

    // layer 1
    sage_layer<true><<<glt, 256, 0, stream>>>(src_emb, tgt_emb, bkt_t, cur_t,
                                              Wl_st1, Wr_st1, b_st1, h_t, NT);
    sage_layer<true><<<gls, 256, 0, stream>>>(tgt_emb, src_emb, bkt_s, cur_s,
                                              Wl_ts1, Wr_ts1, b_ts1, h_s, NS);

    // layer 2: o_t to its own buffer (h_s gather must see original h_t afterwards),
    // o_s in-place over h_s (this call gathers only h_t; own-row read precedes write)
    sage_layer<false><<<glt, 256, 0, stream>>>(h_s, h_t, bkt_t, cur_t,
                                               Wl_st2, Wr_st2, b_st2, o_t, NT);
    sage_layer<false><<<gls, 256, 0, stream>>>(h_t, h_s, bkt_s, cur_s,
                                               Wl_ts2, Wr_ts2, b_ts2, h_s, NS);

    // link scores: o_s[ell_src] . o_t[ell_dst]
    dot_kernel<<<(EL + 15) / 16, 256, 0, stream>>>(h_s, o_t, ell, out, EL);
}

// Round 5
// 998.552 us; speedup vs baseline: 1.5754x; 1.5754x over previous
//
#include <hip/hip_runtime.h>
#include <hip/hip_bf16.h>

#define H 64
#define NXCD 8
#define CAP 64   // Poisson(20) tail @64 ~ 5e-14/node -> no realistic overflow

// ---------------------------------------------------------------- bucket fill
// XCD-partitioned: group g = blockIdx&7 owns node chunk g for BOTH directions.
// One atomic per edge per direction; counts come free in cur_*.
__global__ void bucket_fill(const int* __restrict__ eidx,
                            int* __restrict__ cur_t, int* __restrict__ cur_s,
                            unsigned* __restrict__ bkt_t, unsigned* __restrict__ bkt_s,
                            int E, int NNt, int NNs) {
    int g = blockIdx.x & (NXCD - 1);
    int bg = blockIdx.x >> 3;
    int nbg = gridDim.x >> 3;
    int CSt = (NNt + NXCD - 1) >> 3;
    int CSs = (NNs + NXCD - 1) >> 3;
    int lot = g * CSt, hit = lot + CSt;
    int los = g * CSs, his = los + CSs;
    int stride = nbg * blockDim.x;
    for (int e = bg * blockDim.x + threadIdx.x; e < E; e += stride) {
        int s = eidx[e];
        int d = eidx[E + e];
        if (d >= lot && d < hit) {
            int p = atomicAdd(&cur_t[d], 1);
            if (p < CAP) bkt_t[((size_t)d << 6) + p] = (unsigned)s;
        }
        if (s >= los && s < his) {
            int p = atomicAdd(&cur_s[s], 1);
            if (p < CAP) bkt_s[((size_t)s << 6) + p] = (unsigned)d;
        }
    }
}

// ---------------------------------------------------------------- mean aggregation
// One wave per node, XCD-swizzled so bucket/cur reads hit the L2 their XCD wrote.
// 16 lanes x float4 per feature row; dual accumulator -> 8 outstanding gathers/wave.
// Free-running (no barriers, no launch_bounds) — R2-proven structure.
__global__ void agg_mean(const float* __restrict__ x, const unsigned* __restrict__ bkt,
                         const int* __restrict__ cur, float* __restrict__ out,
                         int n, int CS) {
    int g = blockIdx.x & (NXCD - 1);
    int ib = blockIdx.x >> 3;
    int wv = threadIdx.x >> 6, lane = threadIdx.x & 63;
    int q = lane >> 4, p = lane & 15;
    int local = ib * 4 + wv;
    int node = g * CS + local;
    if (local >= CS || node >= n) return;
    int c = min(cur[node], CAP);
    const unsigned* brow = bkt + ((size_t)node << 6);
    float4 a0 = {0.f, 0.f, 0.f, 0.f};
    float4 a1 = {0.f, 0.f, 0.f, 0.f};
    int k = q;
    for (; k + 4 < c; k += 8) {
        int i0 = (int)brow[k];
        int i1 = (int)brow[k + 4];
        float4 v0 = ((const float4*)(x + (size_t)i0 * H))[p];
        float4 v1 = ((const float4*)(x + (size_t)i1 * H))[p];
        a0.x += v0.x; a0.y += v0.y; a0.z += v0.z; a0.w += v0.w;
        a1.x += v1.x; a1.y += v1.y; a1.z += v1.z; a1.w += v1.w;
    }
    if (k < c) {
        int i0 = (int)brow[k];
        float4 v0 = ((const float4*)(x + (size_t)i0 * H))[p];
        a0.x += v0.x; a0.y += v0.y; a0.z += v0.z; a0.w += v0.w;
    }
    a0.x += a1.x; a0.y += a1.y; a0.z += a1.z; a0.w += a1.w;
#pragma unroll
    for (int m = 16; m <= 32; m <<= 1) {
        a0.x += __shfl_xor(a0.x, m, 64);
        a0.y += __shfl_xor(a0.y, m, 64);
        a0.z += __shfl_xor(a0.z, m, 64);
        a0.w += __shfl_xor(a0.w, m, 64);
    }
    if (q == 0) {
        float inv = 1.f / fmaxf((float)c, 1.f);
        float4 r = {a0.x * inv, a0.y * inv, a0.z * inv, a0.w * inv};
        *(float4*)(out + (size_t)node * H + p * 4) = r;
    }
}

// ---------------------------------------------------------------- fused linear
// out[n][j] = act( sum_k agg[n][k]*Wl[k][j] + x[n][k]*Wr[k][j] + b[j] )
// thread j holds column j of Wl and Wr in registers. Safe in-place (out==agg):
// each row is read fully (store depends on loads) before being written, and
// each row is touched by exactly one wave iteration. (R2-proven, incl. in-place.)
template <bool RELU>
__global__ __launch_bounds__(256, 2) void fused_lin(const float* __restrict__ agg,
                                                    const float* __restrict__ xd,
                                                    const float* __restrict__ Wl,
                                                    const float* __restrict__ Wr,
                                                    const float* __restrict__ b,
                                                    float* __restrict__ out, int n) {
    int tid = threadIdx.x;
    int w = tid >> 6, j = tid & 63;
    float wl[H], wr[H];
#pragma unroll
    for (int k = 0; k < H; k++) {
        wl[k] = Wl[k * H + j];
        wr[k] = Wr[k * H + j];
    }
    float bj = b[j];
    int base = blockIdx.x * 64;
    for (int it = 0; it < 16; ++it) {
        int node = base + it * 4 + w;
        if (node < n) {
            const float4* av = (const float4*)(agg + (size_t)node * H);
            const float4* xv = (const float4*)(xd + (size_t)node * H);
            float acc = bj;
#pragma unroll
            for (int k4 = 0; k4 < 16; k4++) {
                float4 a = av[k4];
                float4 xx = xv[k4];
                acc += a.x * wl[4 * k4 + 0] + a.y * wl[4 * k4 + 1] +
                       a.z * wl[4 * k4 + 2] + a.w * wl[4 * k4 + 3];
                acc += xx.x * wr[4 * k4 + 0] + xx.y * wr[4 * k4 + 1] +
                       xx.z * wr[4 * k4 + 2] + xx.w * wr[4 * k4 + 3];
            }
            out[(size_t)node * H + j] = RELU ? fmaxf(acc, 0.f) : acc;
        }
    }
}

// ---------------------------------------------------------------- link scores
// 16 lanes per label edge, float4 loads, 4 edges per wave
__global__ void dot_kernel(const float* __restrict__ os, const float* __restrict__ ot,
                           const int* __restrict__ ell, float* __restrict__ out, int ne) {
    int wv = threadIdx.x >> 6, lane = threadIdx.x & 63;
    int q = lane >> 4, p = lane & 15;
    int l = (blockIdx.x * 4 + wv) * 4 + q;
    if (l >= ne) return;
    int s = ell[l];
    int d = ell[ne + l];
    float4 a = *(const float4*)(os + (size_t)s * H + p * 4);
    float4 b = *(const float4*)(ot + (size_t)d * H + p * 4);
    float pr = a.x * b.x + a.y * b.y + a.z * b.z + a.w * b.w;
#pragma unroll
    for (int m = 1; m <= 8; m <<= 1) pr += __shfl_xor(pr, m, 64);
    if (p == 0) out[l] = pr;
}

// ----------------------------------------------------------------
static inline size_t alignup(size_t x) { return (x + 255) & ~(size_t)255; }

extern "C" void kernel_launch(void* const* d_in, const int* in_sizes, int n_in,
                              void* d_out, int out_size, void* d_ws, size_t ws_size,
                              hipStream_t stream) {
    const float* src_emb = (const float*)d_in[0];
    const float* tgt_emb = (const float*)d_in[1];
    const float* Wl_st1 = (const float*)d_in[2];
    const float* Wr_st1 = (const float*)d_in[3];
    const float* b_st1 = (const float*)d_in[4];
    const float* Wl_ts1 = (const float*)d_in[5];
    const float* Wr_ts1 = (const float*)d_in[6];
    const float* b_ts1 = (const float*)d_in[7];
    const float* Wl_st2 = (const float*)d_in[8];
    const float* Wr_st2 = (const float*)d_in[9];
    const float* b_st2 = (const float*)d_in[10];
    const float* Wl_ts2 = (const float*)d_in[11];
    const float* Wr_ts2 = (const float*)d_in[12];
    const float* b_ts2 = (const float*)d_in[13];
    const int* eidx = (const int*)d_in[14];
    const int* ell = (const int*)d_in[15];

    const int NS = in_sizes[0] / H;
    const int NT = in_sizes[1] / H;
    const int E = in_sizes[14] / 2;
    const int EL = in_sizes[15] / 2;
    const int NN = NT;  // NS == NT here
    const int CS = (NN + NXCD - 1) / NXCD;

    // ws layout: 128.8 MB total (R4-proven footprint; ws is ~128 MiB).
    // Slots A,B,C are feature buffers; the last gather reuses bkt_t's memory
    // (bkt_t is dead after the layer-2 h_s gather).
    char* ws = (char*)d_ws;
    size_t o_cur = 0;                                       // 2*NN ints
    size_t o_bkt_t = alignup(o_cur + (size_t)2 * NN * 4);   // NN*CAP uints (25.6 MB)
    size_t o_bkt_s = alignup(o_bkt_t + (size_t)NN * CAP * 4);
    size_t o_A = alignup(o_bkt_s + (size_t)NN * CAP * 4);   // NN*H floats
    size_t o_B = alignup(o_A + (size_t)NN * H * 4);
    size_t o_C = alignup(o_B + (size_t)NN * H * 4);

    int* cur_t = (int*)(ws + o_cur);
    int* cur_s = cur_t + NN;
    unsigned* bkt_t = (unsigned*)(ws + o_bkt_t);
    unsigned* bkt_s = (unsigned*)(ws + o_bkt_s);
    float* A = (float*)(ws + o_A);        // agg_t -> h_t
    float* B = (float*)(ws + o_B);        // agg_s -> h_s
    float* C = (float*)(ws + o_C);        // gather(h_s) -> o_t
    float* T = (float*)(ws + o_bkt_t);    // gather(h_t) -> o_s  (reuses bkt_t mem)
    float* out = (float*)d_out;

    hipMemsetAsync(ws + o_cur, 0, (size_t)2 * NN * 4, stream);

    bucket_fill<<<2048, 256, 0, stream>>>(eidx, cur_t, cur_s, bkt_t, bkt_s, E, NT, NS);

    int gagg = NXCD * ((CS + 3) / 4);
    int glin = (NN + 63) / 64;

    // layer 1 (linears in-place over their agg input)
    agg_mean<<<gagg, 256, 0, stream>>>(src_emb, bkt_t, cur_t, A, NT, CS);
    agg_mean<<<gagg, 256, 0, stream>>>(tgt_emb, bkt_s, cur_s, B, NS, CS);
    fused_lin<true><<<glin, 256, 0, stream>>>(A, tgt_emb, Wl_st1, Wr_st1, b_st1, A, NT);  // h_t
    fused_lin<true><<<glin, 256, 0, stream>>>(B, src_emb, Wl_ts1, Wr_ts1, b_ts1, B, NS);  // h_s

    // layer 2
    agg_mean<<<gagg, 256, 0, stream>>>(B, bkt_t, cur_t, C, NT, CS);                        // gather h_s
    fused_lin<false><<<glin, 256, 0, stream>>>(C, A, Wl_st2, Wr_st2, b_st2, C, NT);        // o_t
    agg_mean<<<gagg, 256, 0, stream>>>(A, bkt_s, cur_s, T, NS, CS);                        // gather h_t (into bkt_t mem)
    fused_lin<false><<<glin, 256, 0, stream>>>(T, B, Wl_ts2, Wr_ts2, b_ts2, T, NS);        // o_s

    // link scores: o_s[ell_src] . o_t[ell_dst]
    dot_kernel<<<(EL + 15) / 16, 256, 0, stream>>>(T, C, ell, out, EL);
}